// Round 4
// baseline (1349.920 us; speedup 1.0000x reference)
//
#include <hip/hip_runtime.h>
#include <cstdint>
#include <cstddef>

// Problem dims (fixed): B=256, T=256, D_IN=D_H=D_OUT=512, N=256 steps.
#define BB 256
#define TT 256
#define DD 512
#define MM (BB*TT)   // 65536 rows of (b,t)

// i8 dual-quant scales for h (A-side of recurrence MFMA)
#define S_A (8.0f/127.0f)
#define INV_SA (127.0f/8.0f)
#define S_A2 (S_A/254.0f)
#define INV_SA2 (254.0f*127.0f/8.0f)

typedef __attribute__((ext_vector_type(4))) float f32x4;
typedef __attribute__((ext_vector_type(4))) int i32x4;
typedef __attribute__((ext_vector_type(8))) short short8;
typedef __attribute__((ext_vector_type(8))) __bf16 bf16x8;

__device__ __forceinline__ unsigned short f2bf(float f) {
  union { float f; unsigned int u; } v; v.f = f;
  unsigned int r = v.u + 0x7fffu + ((v.u >> 16) & 1u);
  return (unsigned short)(r >> 16);
}
__device__ __forceinline__ float bf2f(unsigned short u) {
  union { unsigned int u; float f; } v; v.u = ((unsigned int)u) << 16;
  return v.f;
}
__device__ __forceinline__ f32x4 mfma16(short8 a, short8 b, f32x4 c) {
  return __builtin_amdgcn_mfma_f32_16x16x32_bf16(
      __builtin_bit_cast(bf16x8, a), __builtin_bit_cast(bf16x8, b), c, 0, 0, 0);
}
__device__ __forceinline__ i32x4 mfma_i8(long a, long b, i32x4 c) {
  return __builtin_amdgcn_mfma_i32_16x16x32_i8(a, b, c, 0, 0, 0);
}
__device__ __forceinline__ void gload_lds16(const void* g, void* l) {
  __builtin_amdgcn_global_load_lds(
      (const __attribute__((address_space(1))) unsigned int*)g,
      (__attribute__((address_space(3))) unsigned int*)l, 16, 0, 0);
}
// dual-i8 quantize h: q = rint(v/S_A), r = rint((v - q*S_A)/S_A2); pack (q | r<<8)
__device__ __forceinline__ unsigned short quant_i8qr(float v) {
  float q = rintf(v * INV_SA);
  q = fminf(127.0f, fmaxf(-127.0f, q));
  float d = v - q * S_A;
  float r = rintf(d * INV_SA2);
  r = fminf(127.0f, fmaxf(-127.0f, r));
  int qi = (int)q, ri = (int)r;
  return (unsigned short)((qi & 0xFF) | ((ri & 0xFF) << 8));
}

// ---------------------------------------------------------------------------
// pack_x: f32 -> bf16, row-major [M][512]
__global__ __launch_bounds__(256) void pack_x_kernel(
    const float* __restrict__ x, unsigned short* __restrict__ xb) {
  size_t i = ((size_t)blockIdx.x * 256 + threadIdx.x) * 8;
  const float4* p = (const float4*)(x + i);
  float4 a = p[0], b = p[1];
  short8 v;
  v[0] = (short)f2bf(a.x); v[1] = (short)f2bf(a.y);
  v[2] = (short)f2bf(a.z); v[3] = (short)f2bf(a.w);
  v[4] = (short)f2bf(b.x); v[5] = (short)f2bf(b.y);
  v[6] = (short)f2bf(b.z); v[7] = (short)f2bf(b.w);
  *(short8*)(xb + i) = v;
}

// wmax: max|W_h[512:1024][:]| -> wmax scalar (as sortable uint bits)
__global__ __launch_bounds__(256) void wmax_kernel(
    const float* __restrict__ Wh, unsigned int* __restrict__ wmax) {
  size_t i = ((size_t)blockIdx.x * 256 + threadIdx.x) * 8;
  const float* p = Wh + (size_t)512 * DD + i;
  float m = 0.0f;
#pragma unroll
  for (int j = 0; j < 8; ++j) m = fmaxf(m, fabsf(p[j]));
#pragma unroll
  for (int s = 1; s < 64; s <<= 1) m = fmaxf(m, __shfl_xor(m, s));
  if ((threadIdx.x & 63) == 0) atomicMax(wmax, __float_as_uint(m));
}

// pack_w: W[1024][512] f32 -> packed MFMA B-fragments, bf16.
// packed[((nt*32 + kt)*64 + lane)*8 + j] = W[kt*32 + (lane>>4)*8 + j][nt*16 + (lane&15)]
__global__ __launch_bounds__(256) void pack_w_kernel(
    const float* __restrict__ Wh, const float* __restrict__ Wo,
    unsigned short* __restrict__ Whp, unsigned short* __restrict__ Wop) {
  int id = blockIdx.x * 256 + threadIdx.x;     // 0..131071
  int which = id >> 16;
  int rem = id & 65535;                        // nt*2048 + kt*64 + l
  int nt = rem >> 11;
  int kt = (rem >> 6) & 31;
  int l  = rem & 63;
  const float* W = which ? Wo : Wh;
  unsigned short* P = which ? Wop : Whp;
  int n  = nt * 16 + (l & 15);
  int k0 = kt * 32 + ((l >> 4) << 3);
  short8 v;
#pragma unroll
  for (int j = 0; j < 8; ++j) v[j] = (short)f2bf(W[(size_t)(k0 + j) * DD + n]);
  *(short8*)&P[(size_t)rem * 8] = v;
}

// pack_wi: W_h rows 512..1023 -> i8 B-fragments with global scale s_w = wmax/127.
// Wqp[((nt*16 + kt)*64 + l)*8 + j] = i8(W_h[512 + kt*32 + (l>>4)*8 + j][nt*16 + (l&15)])
__global__ __launch_bounds__(256) void pack_wi_kernel(
    const float* __restrict__ Wh, const unsigned int* __restrict__ wmax,
    unsigned char* __restrict__ Wqp) {
  float inv_sw = 127.0f / __uint_as_float(*wmax);
  int id = blockIdx.x * 256 + threadIdx.x;     // 0..32767
  int nt = id >> 10;
  int kt = (id >> 6) & 15;
  int l  = id & 63;
  int n  = nt * 16 + (l & 15);
  int k0 = 512 + kt * 32 + ((l >> 4) << 3);
  unsigned long long u = 0;
#pragma unroll
  for (int j = 0; j < 8; ++j) {
    float w = Wh[(size_t)(k0 + j) * DD + n];
    float q = fminf(127.0f, fmaxf(-127.0f, rintf(w * inv_sw)));
    u |= ((unsigned long long)((unsigned int)((int)q & 0xFF))) << (8 * j);
  }
  *(unsigned long long*)(Wqp + (size_t)id * 8) = u;
}

// ---------------------------------------------------------------------------
// Tiled GEMM: C[M][512] = A[M][K] * Bpacked + bias, K = KTILES*32.
// A rows: k<512 from A1, k>=512 from A2 (both bf16 row-major [M][512]).
// SIG=false: store bf16 (U).  SIG=true: store f32 sigmoid (final out).
template <int KTILES, bool SIG>
__global__ __launch_bounds__(256, 2) void gemm_bt(
    const unsigned short* __restrict__ A1, const unsigned short* __restrict__ A2,
    const unsigned short* __restrict__ Bp, const float* __restrict__ bias,
    void* __restrict__ OutP) {
  __shared__ unsigned short Alds[2][8 * 64 * 8];  // frag-order, 8KB per buf
  const int tid = threadIdx.x, lane = tid & 63, wave = tid >> 6;
  const int m0 = blockIdx.x * 128, n0 = blockIdx.y * 128;
  const int wmt = (wave >> 1) * 4;  // first m-tile of wave (0 or 4)
  const int wnt = (wave & 1) * 4;   // first n-tile of wave (0 or 4)

  auto srcp = [&](int s, int kt) -> const unsigned short* {
    int mt = s >> 6, l = s & 63;
    int row = m0 + mt * 16 + (l & 15);
    int k = kt * 32 + ((l >> 4) << 3);
    if (KTILES == 32 && k >= 512) return A2 + (size_t)row * DD + (k - 512);
    return A1 + (size_t)row * DD + k;
  };

  gload_lds16(srcp(tid, 0), &Alds[0][tid * 8]);
  gload_lds16(srcp(tid + 256, 0), &Alds[0][(tid + 256) * 8]);
  __syncthreads();

  f32x4 acc[4][4];
#pragma unroll
  for (int i = 0; i < 4; ++i)
#pragma unroll
    for (int j = 0; j < 4; ++j) acc[i][j] = (f32x4)0.0f;

  int buf = 0;
  for (int kt = 0; kt < KTILES; ++kt) {
    if (kt + 1 < KTILES) {
      gload_lds16(srcp(tid, kt + 1), &Alds[buf ^ 1][tid * 8]);
      gload_lds16(srcp(tid + 256, kt + 1), &Alds[buf ^ 1][(tid + 256) * 8]);
    }
    short8 bfr[4], afr[4];
#pragma unroll
    for (int j = 0; j < 4; ++j) {
      int nt = (n0 >> 4) + wnt + j;
      bfr[j] = *(const short8*)(Bp + (((size_t)nt * 32 + kt) * 64 + lane) * 8);
    }
#pragma unroll
    for (int i = 0; i < 4; ++i)
      afr[i] = *(const short8*)&Alds[buf][((wmt + i) * 64 + lane) * 8];
#pragma unroll
    for (int i = 0; i < 4; ++i)
#pragma unroll
      for (int j = 0; j < 4; ++j) acc[i][j] = mfma16(afr[i], bfr[j], acc[i][j]);
    __syncthreads();
    buf ^= 1;
  }

  float bv[4];
#pragma unroll
  for (int j = 0; j < 4; ++j) bv[j] = bias[n0 + (wnt + j) * 16 + (lane & 15)];
#pragma unroll
  for (int i = 0; i < 4; ++i) {
#pragma unroll
    for (int j = 0; j < 4; ++j) {
      int colg = n0 + (wnt + j) * 16 + (lane & 15);
#pragma unroll
      for (int r = 0; r < 4; ++r) {
        int rowg = m0 + (wmt + i) * 16 + ((lane >> 4) << 2) + r;
        float v = acc[i][j][r] + bv[j];
        if (SIG) {
          ((float*)OutP)[(size_t)rowg * DD + colg] = 1.0f / (1.0f + __expf(-v));
        } else {
          float vn = __shfl_xor(v, 1);
          if (!(lane & 1)) {
            unsigned int pk = (unsigned int)f2bf(v) | ((unsigned int)f2bf(vn) << 16);
            *(unsigned int*)((unsigned short*)OutP + (size_t)rowg * DD + colg) = pk;
          }
        }
      }
    }
  }
}

// ---------------------------------------------------------------------------
// Sequential recurrence, i8 W_hh (max-scaled) held entirely in registers.
// 16 blocks x 16 batch rows, 8 waves (wave w owns h-cols [64w, 64w+64)).
// h_{t+1} = U[:,t,:] + h_t @ W_hh; h_t carried as dual-i8 (q + r/254) in LDS.
// i8 x i8 -> i32 MFMA is exact; only error is W/h quantization noise.
// Stores H[:,t,:] = h_t (bf16) for t=0..255. h_final left to hfin_fix.
#define HST 520  // u16 stride per row (512 + 8 pad); 1040B, 16B-multiple
__global__ __launch_bounds__(512, 2) void rnn_rec_i8(
    const unsigned short* __restrict__ U, const unsigned char* __restrict__ Wqp,
    const unsigned int* __restrict__ wmax, const float* __restrict__ h0,
    unsigned short* __restrict__ H) {
  __shared__ unsigned short HB[2][16 * HST];  // interleaved (q | r<<8), swizzled
  const int tid = threadIdx.x, lane = tid & 63, wave = tid >> 6;
  const int r0 = blockIdx.x * 16;
  const int cbase = wave * 64;  // wave's first h-col; nt = wave*4 + j

  const float s_w = __uint_as_float(*wmax) * (1.0f / 127.0f);
  const float f1 = s_w * S_A;    // scale for q-accumulator
  const float f2 = s_w * S_A2;   // scale for r-accumulator

  // ---- load i8 W fragments into registers: 16 kt x 4 j = 128 VGPRs
  long Wq[16][4];
#pragma unroll
  for (int kt = 0; kt < 16; ++kt)
#pragma unroll
    for (int j = 0; j < 4; ++j)
      Wq[kt][j] = *(const long*)(Wqp +
          (((size_t)(wave * 4 + j) * 16 + kt) * 64 + lane) * 8);

  // ---- init: h0 -> HB[0] (dual-i8, swizzled) and H[:,0] (bf16)
  {
    int row = tid >> 5, c0 = (tid & 31) * 16;
    const float* hp = h0 + (size_t)(r0 + row) * DD + c0;
    int sw = (row & 8) << 1;
    unsigned int hb[8];
#pragma unroll
    for (int j = 0; j < 16; ++j) {
      float v = hp[j];
      HB[0][row * HST + ((c0 + j) ^ sw)] = quant_i8qr(v);
      if (j & 1) hb[j >> 1] |= ((unsigned int)f2bf(v)) << 16;
      else       hb[j >> 1]  = (unsigned int)f2bf(v);
    }
    unsigned short* hg = H + ((size_t)(r0 + row) * TT + 0) * DD + c0;
    *(uint4*)hg       = *(uint4*)&hb[0];
    *(uint4*)(hg + 8) = *(uint4*)&hb[4];
  }

  // ---- prefetch U[:,0]
  unsigned short ucur[4][4];
#pragma unroll
  for (int j = 0; j < 4; ++j)
#pragma unroll
    for (int r = 0; r < 4; ++r)
      ucur[j][r] = U[((size_t)(r0 + ((lane >> 4) << 2) + r) * TT + 0) * DD +
                     cbase + j * 16 + (lane & 15)];
  __syncthreads();

  int buf = 0;
  const int rdsw = (lane & 8) << 1;               // read-row swizzle (row = lane&15)
  const int rbase = (lane & 15) * HST;
  for (int t = 0; t < TT - 1; ++t) {
    // prefetch U[:, t+1]
    unsigned short unxt[4][4];
#pragma unroll
    for (int j = 0; j < 4; ++j)
#pragma unroll
      for (int r = 0; r < 4; ++r)
        unxt[j][r] = U[((size_t)(r0 + ((lane >> 4) << 2) + r) * TT + (t + 1)) * DD +
                       cbase + j * 16 + (lane & 15)];

    i32x4 accq[4], accr[4];
#pragma unroll
    for (int j = 0; j < 4; ++j)
#pragma unroll
      for (int r = 0; r < 4; ++r) { accq[j][r] = 0; accr[j][r] = 0; }

#pragma unroll
    for (int kt = 0; kt < 16; ++kt) {
      int k0 = kt * 32 + ((lane >> 4) << 3);
      int4 w = *(const int4*)&HB[buf][rbase + (k0 ^ rdsw)];
      unsigned int qlo = __builtin_amdgcn_perm(w.y, w.x, 0x06040200u);
      unsigned int qhi = __builtin_amdgcn_perm(w.w, w.z, 0x06040200u);
      unsigned int rlo = __builtin_amdgcn_perm(w.y, w.x, 0x07050301u);
      unsigned int rhi = __builtin_amdgcn_perm(w.w, w.z, 0x07050301u);
      long aq = (long)(((unsigned long long)qhi << 32) | qlo);
      long ar = (long)(((unsigned long long)rhi << 32) | rlo);
#pragma unroll
      for (int j = 0; j < 4; ++j) {
        accq[j] = mfma_i8(aq, Wq[kt][j], accq[j]);
        accr[j] = mfma_i8(ar, Wq[kt][j], accr[j]);
      }
    }

    // ---- write phase: h_{t+1} -> HB[buf^1] (dual-i8 scatter) + H global (bf16)
#pragma unroll
    for (int j = 0; j < 4; ++j) {
      int c = cbase + j * 16 + (lane & 15);
#pragma unroll
      for (int r = 0; r < 4; ++r) {
        int row = ((lane >> 4) << 2) + r;
        float v = bf2f(ucur[j][r]) + f1 * (float)accq[j][r] + f2 * (float)accr[j][r];
        // bf16 -> H[:, t+1]
        float vn = __shfl_xor(v, 1);
        if (!(lane & 1)) {
          unsigned int pk = (unsigned int)f2bf(v) | ((unsigned int)f2bf(vn) << 16);
          *(unsigned int*)(H + ((size_t)(r0 + row) * TT + (t + 1)) * DD + c) = pk;
        }
        // dual-i8 -> LDS (swizzled col), conflict-free u16 scatter
        HB[buf ^ 1][row * HST + (c ^ ((row & 8) << 1))] = quant_i8qr(v);
      }
    }
    // lgkm-only barrier (skip the vmcnt(0) drain __syncthreads would emit:
    // H stores are fire-and-forget, U prefetch waits are inserted at use)
    asm volatile("s_waitcnt lgkmcnt(0)" ::: "memory");
    __builtin_amdgcn_s_barrier();
    __builtin_amdgcn_sched_barrier(0);
    buf ^= 1;
#pragma unroll
    for (int j = 0; j < 4; ++j)
#pragma unroll
      for (int r = 0; r < 4; ++r) ucur[j][r] = unxt[j][r];
  }
}

// ---------------------------------------------------------------------------
// hfin_fix: h_final = U[:,255] + H[:,255] @ W_hh, all-bf16 (clean final step
// for the unbounded f32 h_final output). 16 blocks x 512 threads.
__global__ __launch_bounds__(512) void hfin_fix(
    const unsigned short* __restrict__ U, const unsigned short* __restrict__ Whp,
    const unsigned short* __restrict__ H, float* __restrict__ hfin) {
  __shared__ unsigned short Hl[16 * HST];
  const int tid = threadIdx.x, lane = tid & 63, wave = tid >> 6;
  const int r0 = blockIdx.x * 16;
  {
    int row = tid >> 5, c0 = (tid & 31) * 16;
    const unsigned short* src = H + ((size_t)(r0 + row) * TT + 255) * DD + c0;
    *(short8*)&Hl[row * HST + c0]     = *(const short8*)src;
    *(short8*)&Hl[row * HST + c0 + 8] = *(const short8*)(src + 8);
  }
  f32x4 acc[4];
#pragma unroll
  for (int j = 0; j < 4; ++j)
#pragma unroll
    for (int r = 0; r < 4; ++r)
      acc[j][r] = bf2f(U[((size_t)(r0 + ((lane >> 4) << 2) + r) * TT + 255) * DD +
                         wave * 64 + j * 16 + (lane & 15)]);
  __syncthreads();
#pragma unroll
  for (int kt = 0; kt < 16; ++kt) {
    short8 a = *(const short8*)&Hl[(lane & 15) * HST + kt * 32 + ((lane >> 4) << 3)];
#pragma unroll
    for (int j = 0; j < 4; ++j) {
      short8 b = *(const short8*)(Whp +
                 (((size_t)(wave * 4 + j) * 32 + 16 + kt) * 64 + lane) * 8);
      acc[j] = mfma16(a, b, acc[j]);
    }
  }
#pragma unroll
  for (int j = 0; j < 4; ++j)
#pragma unroll
    for (int r = 0; r < 4; ++r)
      hfin[(size_t)(r0 + ((lane >> 4) << 2) + r) * DD + wave * 64 + j * 16 +
           (lane & 15)] = acc[j][r];
}

// ---------------------------------------------------------------------------
extern "C" void kernel_launch(void* const* d_in, const int* in_sizes, int n_in,
                              void* d_out, int out_size, void* d_ws, size_t ws_size,
                              hipStream_t stream) {
  const float* x  = (const float*)d_in[0];
  const float* h0 = (const float*)d_in[1];
  const float* Wh = (const float*)d_in[2];
  const float* bh = (const float*)d_in[3];
  const float* Wo = (const float*)d_in[4];
  const float* bo = (const float*)d_in[5];
  // d_in[6] = N (always 256 for this problem)

  char* ws = (char*)d_ws;
  unsigned short* xb  = (unsigned short*)(ws);                  // 67108864 B
  unsigned short* U   = (unsigned short*)(ws + 67108864);       // 67108864 B
  unsigned short* H   = (unsigned short*)(ws + 134217728);      // 67108864 B
  unsigned short* Whp = (unsigned short*)(ws + 201326592);      // 1048576 B
  unsigned short* Wop = (unsigned short*)(ws + 202375168);      // 1048576 B
  unsigned char*  Wqp = (unsigned char*) (ws + 203423744);      // 262144 B
  unsigned int*   wmx = (unsigned int*)  (ws + 203685888);      // 4 B

  float* out  = (float*)d_out;                  // [B,T,512]
  float* hfin = out + (size_t)MM * DD;          // [B,512]

  hipMemsetAsync(wmx, 0, 4, stream);  // ws is re-poisoned each launch
  pack_x_kernel<<<dim3(MM * DD / (256 * 8)), dim3(256), 0, stream>>>(x, xb);
  wmax_kernel<<<dim3(128), dim3(256), 0, stream>>>(Wh, wmx);
  pack_w_kernel<<<dim3(512), dim3(256), 0, stream>>>(Wh, Wo, Whp, Wop);
  pack_wi_kernel<<<dim3(128), dim3(256), 0, stream>>>(Wh, wmx, Wqp);
  // U = x @ W_h[:512] + b_h   (bf16 out)
  gemm_bt<16, false><<<dim3(MM / 128, 4), dim3(256), 0, stream>>>(xb, xb, Whp, bh, (void*)U);
  // sequential recurrence over T (i8 W in registers, exact i32 accumulation)
  rnn_rec_i8<<<dim3(16), dim3(512), 0, stream>>>(U, Wqp, wmx, h0, H);
  // h_final recomputed in bf16 from H[:,255]
  hfin_fix<<<dim3(16), dim3(512), 0, stream>>>(U, Whp, H, hfin);
  // out = sigmoid([x | H] @ W_o + b_o)  (f32 out)
  gemm_bt<32, true><<<dim3(MM / 128, 4), dim3(256), 0, stream>>>(xb, H, Wop, bo, (void*)out);
}